// Round 4
// baseline (1009.560 us; speedup 1.0000x reference)
//
#include <hip/hip_runtime.h>

// Sinkhorn, N=4096, D=2, P=1, eps=0.1, 50 iters — persistent cooperative kernel.
// Round-7: round-6 (594 us profiled, passed) minus the LDS W-stage.
//  - W (the other side's u/v vector) is loaded per-wave DIRECTLY into registers:
//    16 x 8B coherent loads per lane (its 8 j-tiles x 4 consecutive floats),
//    issued up front; scale folds into the compute as fma(W, S_L2E, -D).
//    Removes per phase: 4-load stage + LDS write + one __syncthreads + the
//    stage hop on the critical path. Costs 8x redundant MALL reads (128KB/CU,
//    ~0.4us port time, TLP-hidden) — explicit gamble, revert if flat.
//  - Dreg u-phase distance cache, persistent coords in LDS (v-phase + Dreg
//    precompute), replicated-release tree barrier, combine: verbatim round-6.

#define NPTS    4096
#define EPS_F   0.1f
#define S_L2E   14.426950408889634f     /* log2(e)/eps */
#define INV_SL  0.0693147180559945f     /* 1/S_L2E = eps*ln2 */
#define A_LOGMU (-0.8317725207f)        /* eps * ln(1/N + 1e-8) */
#define N_ITER  50
#define NBLK    256
#define TPB     1024
#define WPB     (TPB / 64)              /* 16 waves/block */
#define RPW     2                       /* rows per wave (wave-pair shares rows) */
#define HALFC   2048                    /* columns per wave (pair splits 4096) */
#define NJT     (HALFC / 256)           /* 8 j-tiles of 64 lanes x 4 cols */
#define NLEAF   16
#define BSTRIDE 64                      /* ints between barrier words = 256 B */
/* layout: leaf i at i*BSTRIDE (i<16); root at 16*BSTRIDE; replica r at (17+r) */
#define BAR_INTS ((NLEAF + 1 + NLEAF) * BSTRIDE)

typedef unsigned long long u64;
typedef float f4u __attribute__((ext_vector_type(4), aligned(4)));

__device__ __forceinline__ float fexp2(float x) {
#if __has_builtin(__builtin_amdgcn_exp2f)
  return __builtin_amdgcn_exp2f(x);
#else
  float r;
  asm("v_exp_f32 %0, %1" : "=v"(r) : "v"(x));
  return r;
#endif
}

__device__ __forceinline__ float coh_load(const float* p) {
  return __hip_atomic_load(p, __ATOMIC_RELAXED, __HIP_MEMORY_SCOPE_AGENT);
}
__device__ __forceinline__ void coh_store(float* p, float x) {
  __hip_atomic_store(p, x, __ATOMIC_RELAXED, __HIP_MEMORY_SCOPE_AGENT);
}
__device__ __forceinline__ u64 coh_load64(const u64* p) {
  return __hip_atomic_load(const_cast<u64*>(p), __ATOMIC_RELAXED,
                           __HIP_MEMORY_SCOPE_AGENT);
}
__device__ __forceinline__ float val_lo(u64 w) {
  return __uint_as_float((unsigned)w);
}
__device__ __forceinline__ float val_hi(u64 w) {
  return __uint_as_float((unsigned)(w >> 32));
}

__device__ __forceinline__ float wave_sum64(float x) {
#pragma unroll
  for (int off = 32; off > 0; off >>= 1) x += __shfl_xor(x, off, 64);
  return x;
}

// Tree barrier, all ops RELAXED AGENT — verbatim round-6 (verified).
__device__ __forceinline__ void grid_barrier(int* bar, int k) {
  __syncthreads();
  if (threadIdx.x == 0) {
    int* leaf = bar + (blockIdx.x & (NLEAF - 1)) * BSTRIDE;
    const int old = __hip_atomic_fetch_add(leaf, 1, __ATOMIC_RELAXED,
                                           __HIP_MEMORY_SCOPE_AGENT);
    if (old == NLEAF * k - 1) {
      int* root = bar + NLEAF * BSTRIDE;
      const int ro = __hip_atomic_fetch_add(root, 1, __ATOMIC_RELAXED,
                                            __HIP_MEMORY_SCOPE_AGENT);
      if (ro == NLEAF * k - 1) {
#pragma unroll
        for (int rr = 0; rr < NLEAF; ++rr)
          __hip_atomic_store(bar + (NLEAF + 1 + rr) * BSTRIDE, k,
                             __ATOMIC_RELAXED, __HIP_MEMORY_SCOPE_AGENT);
      }
    }
    int* rep = bar + (NLEAF + 1 + (blockIdx.x & (NLEAF - 1))) * BSTRIDE;
    while (__hip_atomic_load(rep, __ATOMIC_RELAXED,
                             __HIP_MEMORY_SCOPE_AGENT) < k)
      __builtin_amdgcn_s_sleep(1);
  }
  __syncthreads();
}

// One-time coord stage: scaled column coords into LDS (4 cols/thread).
__device__ __forceinline__ void stageCoords(const float* __restrict__ colp,
                                            float* __restrict__ sC0,
                                            float* __restrict__ sC1, int tid) {
  const int c = tid * 4;
  const float4 a = ((const float4*)colp)[(c >> 1) + 0];  // (x0,y0,x1,y1)
  const float4 b = ((const float4*)colp)[(c >> 1) + 1];  // (x2,y2,x3,y3)
  float4 C0, C1;
  C0.x = a.x * S_L2E; C0.y = a.z * S_L2E; C0.z = b.x * S_L2E; C0.w = b.z * S_L2E;
  C1.x = a.y * S_L2E; C1.y = a.w * S_L2E; C1.z = b.y * S_L2E; C1.w = b.w * S_L2E;
  *(float4*)(sC0 + c) = C0;
  *(float4*)(sC1 + c) = C1;
}

// Load this lane's 32-float W working set (8 tiles x 4 floats) as 16 coherent
// 8B loads, all issued up front (latency hidden by 16 waves/CU TLP).
#define LOAD_WP(win)                                                     \
  u64 Wp[2 * NJT];                                                       \
  {                                                                      \
    const u64* __restrict__ w64 = (const u64*)(win);                     \
    const int b2 = base >> 1;                                            \
    _Pragma("unroll") for (int jt = 0; jt < NJT; ++jt) {                 \
      Wp[2 * jt + 0] = coh_load64(w64 + b2 + jt * 128 + 0);              \
      Wp[2 * jt + 1] = coh_load64(w64 + b2 + jt * 128 + 1);              \
    }                                                                    \
  }

// u-phase: W direct from registers, D from Dreg. Scale folded into FMA.
__device__ __forceinline__ void phaseU(const float* __restrict__ win,
                                       const float (&Dreg)[NJT][RPW][4],
                                       float (*sPart)[RPW],
                                       float* __restrict__ wout,
                                       int row0blk, int wv, int lane, int tid,
                                       int base) {
  LOAD_WP(win)
  float acc0 = 0.f, acc1 = 0.f;
#pragma unroll
  for (int jt = 0; jt < NJT; ++jt) {
    const float w0 = val_lo(Wp[2 * jt]),     w1 = val_hi(Wp[2 * jt]);
    const float w2 = val_lo(Wp[2 * jt + 1]), w3 = val_hi(Wp[2 * jt + 1]);
    acc0 += (fexp2(fmaf(w0, S_L2E, -Dreg[jt][0][0])) +
             fexp2(fmaf(w1, S_L2E, -Dreg[jt][0][1]))) +
            (fexp2(fmaf(w2, S_L2E, -Dreg[jt][0][2])) +
             fexp2(fmaf(w3, S_L2E, -Dreg[jt][0][3])));
    acc1 += (fexp2(fmaf(w0, S_L2E, -Dreg[jt][1][0])) +
             fexp2(fmaf(w1, S_L2E, -Dreg[jt][1][1]))) +
            (fexp2(fmaf(w2, S_L2E, -Dreg[jt][1][2])) +
             fexp2(fmaf(w3, S_L2E, -Dreg[jt][1][3])));
  }
  const float S0 = wave_sum64(acc0);
  const float S1 = wave_sum64(acc1);
  if (lane == 0) { sPart[wv][0] = S0; sPart[wv][1] = S1; }
  __syncthreads();
  if (tid < 16) {
    const int p = tid >> 1, r = tid & 1;
    const float S = sPart[2 * p][r] + sPart[2 * p + 1][r];
    coh_store(wout + row0blk + p * RPW + r, A_LOGMU - EPS_F * __logf(S));
  }
}

// v-phase: W direct from registers, coords from persistent LDS.
__device__ __forceinline__ void phaseV(const float* __restrict__ rx,
                                       const float* __restrict__ ry,
                                       const float* __restrict__ win,
                                       const float* __restrict__ sC0,
                                       const float* __restrict__ sC1,
                                       float (*sPart)[RPW],
                                       float* __restrict__ wout,
                                       int row0blk, int wv, int lane, int tid,
                                       int base) {
  LOAD_WP(win)
  float acc0 = 0.f, acc1 = 0.f;
#pragma unroll
  for (int jt = 0; jt < NJT; ++jt) {
    const int j = base + jt * 256;
    const float4 C0 = *(const float4*)(sC0 + j);
    const float4 C1 = *(const float4*)(sC1 + j);
    const float w0 = val_lo(Wp[2 * jt]),     w1 = val_hi(Wp[2 * jt]);
    const float w2 = val_lo(Wp[2 * jt + 1]), w3 = val_hi(Wp[2 * jt + 1]);
    {
      const float a0 = fmaf(w0, S_L2E, -fabsf(rx[0] - C0.x)) - fabsf(ry[0] - C1.x);
      const float a1 = fmaf(w1, S_L2E, -fabsf(rx[0] - C0.y)) - fabsf(ry[0] - C1.y);
      const float a2 = fmaf(w2, S_L2E, -fabsf(rx[0] - C0.z)) - fabsf(ry[0] - C1.z);
      const float a3 = fmaf(w3, S_L2E, -fabsf(rx[0] - C0.w)) - fabsf(ry[0] - C1.w);
      acc0 += (fexp2(a0) + fexp2(a1)) + (fexp2(a2) + fexp2(a3));
    }
    {
      const float a0 = fmaf(w0, S_L2E, -fabsf(rx[1] - C0.x)) - fabsf(ry[1] - C1.x);
      const float a1 = fmaf(w1, S_L2E, -fabsf(rx[1] - C0.y)) - fabsf(ry[1] - C1.y);
      const float a2 = fmaf(w2, S_L2E, -fabsf(rx[1] - C0.z)) - fabsf(ry[1] - C1.z);
      const float a3 = fmaf(w3, S_L2E, -fabsf(rx[1] - C0.w)) - fabsf(ry[1] - C1.w);
      acc1 += (fexp2(a0) + fexp2(a1)) + (fexp2(a2) + fexp2(a3));
    }
  }
  const float S0 = wave_sum64(acc0);
  const float S1 = wave_sum64(acc1);
  if (lane == 0) { sPart[wv][0] = S0; sPart[wv][1] = S1; }
  __syncthreads();
  if (tid < 16) {
    const int p = tid >> 1, r = tid & 1;
    const float S = sPart[2 * p][r] + sPart[2 * p + 1][r];
    coh_store(wout + row0blk + p * RPW + r, A_LOGMU - EPS_F * __logf(S));
  }
}

__global__ void __launch_bounds__(TPB, 4)
sinkhorn_main(const float* __restrict__ x, const float* __restrict__ y,
              float* __restrict__ u, float* __restrict__ v,
              float* __restrict__ out, int* __restrict__ bar) {
  __shared__ float sC0y[NPTS], sC1y[NPTS];    // y cols (Dreg precompute)
  __shared__ float sC0x[NPTS], sC1x[NPTS];    // x cols (v-phase)
  __shared__ float sPart[WPB][RPW];
  __shared__ float sCost[WPB];

  const int tid  = threadIdx.x;
  const int wv   = tid >> 6;
  const int lane = tid & 63;
  const int row0blk = blockIdx.x * (WPB / 2) * RPW;        // 16 rows per block
  const int row0 = row0blk + (wv >> 1) * RPW;              // this wave's rows
  const int base = (wv & 1) * HALFC + lane * 4;

  float rxu[RPW], ryu[RPW], rxv[RPW], ryv[RPW];
#pragma unroll
  for (int r = 0; r < RPW; ++r) {
    const float2 xr = ((const float2*)x)[row0 + r];
    const float2 yr = ((const float2*)y)[row0 + r];
    rxu[r] = xr.x * S_L2E;  ryu[r] = xr.y * S_L2E;
    rxv[r] = yr.x * S_L2E;  ryv[r] = yr.y * S_L2E;
  }

  stageCoords(y, sC0y, sC1y, tid);
  stageCoords(x, sC0x, sC1x, tid);
  __syncthreads();

  // Iteration-invariant scaled distances for this thread's u-phase footprint.
  float Dreg[NJT][RPW][4];
#pragma unroll
  for (int jt = 0; jt < NJT; ++jt) {
    const int j = base + jt * 256;
    const float4 C0 = *(const float4*)(sC0y + j);
    const float4 C1 = *(const float4*)(sC1y + j);
#pragma unroll
    for (int r = 0; r < RPW; ++r) {
      Dreg[jt][r][0] = fabsf(rxu[r] - C0.x) + fabsf(ryu[r] - C1.x);
      Dreg[jt][r][1] = fabsf(rxu[r] - C0.y) + fabsf(ryu[r] - C1.y);
      Dreg[jt][r][2] = fabsf(rxu[r] - C0.z) + fabsf(ryu[r] - C1.z);
      Dreg[jt][r][3] = fabsf(rxu[r] - C0.w) + fabsf(ryu[r] - C1.w);
    }
  }

  int k = 0;
  for (int it = 0; it < N_ITER; ++it) {
    phaseU(v, Dreg, sPart, u, row0blk, wv, lane, tid, base);
    grid_barrier(bar, ++k);
    phaseV(rxv, ryv, u, sC0x, sC1x, sPart, v, row0blk, wv, lane, tid, base);
    grid_barrier(bar, ++k);
  }

  // ---- output: out[0]=cost, out[1..]=pi, out[1+N*N..]=C ----
  float* __restrict__ pi = out + 1;
  float* __restrict__ cm = out + 1 + (size_t)NPTS * NPTS;
  float uu[RPW];
#pragma unroll
  for (int r = 0; r < RPW; ++r) uu[r] = coh_load(u + row0 + r) * S_L2E;

  LOAD_WP(v)                       // final v (barrier k=100 made it visible)
  float costacc = 0.f;
#pragma unroll
  for (int jt = 0; jt < NJT; ++jt) {
    const int j = base + jt * 256;
    const float w0 = val_lo(Wp[2 * jt]),     w1 = val_hi(Wp[2 * jt]);
    const float w2 = val_lo(Wp[2 * jt + 1]), w3 = val_hi(Wp[2 * jt + 1]);
#pragma unroll
    for (int r = 0; r < RPW; ++r) {
      const float s0 = Dreg[jt][r][0];
      const float s1 = Dreg[jt][r][1];
      const float s2 = Dreg[jt][r][2];
      const float s3 = Dreg[jt][r][3];
      const float p0 = fexp2(fmaf(w0, S_L2E, uu[r] - s0));
      const float p1 = fexp2(fmaf(w1, S_L2E, uu[r] - s1));
      const float p2 = fexp2(fmaf(w2, S_L2E, uu[r] - s2));
      const float p3 = fexp2(fmaf(w3, S_L2E, uu[r] - s3));
      costacc = fmaf(p0, s0, costacc);
      costacc = fmaf(p1, s1, costacc);
      costacc = fmaf(p2, s2, costacc);
      costacc = fmaf(p3, s3, costacc);
      const size_t off = (size_t)(row0 + r) * NPTS + j;
      f4u pv; pv.x = p0; pv.y = p1; pv.z = p2; pv.w = p3;
      f4u cv; cv.x = s0 * INV_SL; cv.y = s1 * INV_SL;
      cv.z = s2 * INV_SL; cv.w = s3 * INV_SL;
      *(f4u*)(pi + off) = pv;   // out+1 base is 4B-aligned; f4u is aligned(4)
      *(f4u*)(cm + off) = cv;
    }
  }
  const float cw = wave_sum64(costacc);
  if (lane == 0) sCost[wv] = cw;
  __syncthreads();
  if (tid == 0) {
    float c = 0.f;
#pragma unroll
    for (int w = 0; w < WPB; ++w) c += sCost[w];
    atomicAdd(out, c * INV_SL);
  }
}

__global__ void sinkhorn_init(float* __restrict__ v, int* __restrict__ bar,
                              float* __restrict__ out) {
  const int i = blockIdx.x * blockDim.x + threadIdx.x;
  if (i < NPTS) coh_store(v + i, 0.f);
  if (i < BAR_INTS)
    __hip_atomic_store(bar + i, 0, __ATOMIC_RELAXED, __HIP_MEMORY_SCOPE_AGENT);
  if (i == 0) out[0] = 0.f;
}

extern "C" void kernel_launch(void* const* d_in, const int* in_sizes, int n_in,
                              void* d_out, int out_size, void* d_ws, size_t ws_size,
                              hipStream_t stream) {
  const float* x = (const float*)d_in[0];
  const float* y = (const float*)d_in[1];
  float* u = (float*)d_ws;
  float* v = u + NPTS;
  int* bar = (int*)(v + NPTS);
  float* out = (float*)d_out;

  sinkhorn_init<<<dim3(16), dim3(256), 0, stream>>>(v, bar, out);

  void* args[6];
  args[0] = (void*)&x;
  args[1] = (void*)&y;
  args[2] = (void*)&u;
  args[3] = (void*)&v;
  args[4] = (void*)&out;
  args[5] = (void*)&bar;
  hipLaunchCooperativeKernel((void*)sinkhorn_main, dim3(NBLK), dim3(TPB),
                             args, 0, stream);
}

// Round 5
// 688.468 us; speedup vs baseline: 1.4664x; 1.4664x over previous
//
#include <hip/hip_runtime.h>

// Sinkhorn, N=4096, D=2, P=1, eps=0.1, 50 iters — persistent cooperative kernel.
// Round-8: round-6 baseline (594 us profiled, VERIFIED) + flattened barrier.
// Round-7's per-wave register W-staging is REVERTED: its 64-bit agent-scope
// atomic loads bypassed MALL caching (FETCH 7MB -> 1.09GB, dur 916us). The
// stage-once-per-block LDS pattern is load-bearing for coherent traffic.
// Single change vs round-6: grid_barrier drops the root-counter hop. Leaf
// winners publish leafdone[leaf]=k directly; spinners poll all 16 flags
// (monotone, ABA-free). One fewer serial MALL round-trip per barrier.

#define NPTS    4096
#define EPS_F   0.1f
#define S_L2E   14.426950408889634f     /* log2(e)/eps */
#define INV_SL  0.0693147180559945f     /* 1/S_L2E = eps*ln2 */
#define A_LOGMU (-0.8317725207f)        /* eps * ln(1/N + 1e-8) */
#define N_ITER  50
#define NBLK    256
#define TPB     1024
#define WPB     (TPB / 64)              /* 16 waves/block */
#define RPW     2                       /* rows per wave (wave-pair shares rows) */
#define HALFC   2048                    /* columns per wave (pair splits 4096) */
#define NJT     (HALFC / 256)           /* 8 j-tiles of 64 lanes x 4 cols */
#define NLEAF   16
#define BSTRIDE 64                      /* ints between barrier words = 256 B */
/* layout: leaf i at i*BSTRIDE (i<16); [16] unused; leafdone r at (17+r)*BSTRIDE */
#define BAR_INTS ((NLEAF + 1 + NLEAF) * BSTRIDE)

typedef float f4u __attribute__((ext_vector_type(4), aligned(4)));

__device__ __forceinline__ float fexp2(float x) {
#if __has_builtin(__builtin_amdgcn_exp2f)
  return __builtin_amdgcn_exp2f(x);
#else
  float r;
  asm("v_exp_f32 %0, %1" : "=v"(r) : "v"(x));
  return r;
#endif
}

__device__ __forceinline__ float coh_load(const float* p) {
  return __hip_atomic_load(p, __ATOMIC_RELAXED, __HIP_MEMORY_SCOPE_AGENT);
}
__device__ __forceinline__ void coh_store(float* p, float x) {
  __hip_atomic_store(p, x, __ATOMIC_RELAXED, __HIP_MEMORY_SCOPE_AGENT);
}

__device__ __forceinline__ float wave_sum64(float x) {
#pragma unroll
  for (int off = 32; off > 0; off >>= 1) x += __shfl_xor(x, off, 64);
  return x;
}

// Flattened tree barrier, all ops RELAXED AGENT. __syncthreads before arrival
// drains this block's coherent u/v stores (s_waitcnt vmcnt(0) precedes
// s_barrier). leaf[b&15]: 16 RMWs each on parallel lines; each leaf's winner
// (old == 16k-1) stores leafdone[leaf] = k; every block spins polling all 16
// leafdone flags (16 independent lines, loads pipeline into ~1 round-trip).
// Monotone counters/flags => stale reads only cause extra spins, never early
// release. No root hop: one fewer serial MALL round-trip than round-6.
__device__ __forceinline__ void grid_barrier(int* bar, int k) {
  __syncthreads();
  if (threadIdx.x == 0) {
    const int myleaf = blockIdx.x & (NLEAF - 1);
    int* leaf = bar + myleaf * BSTRIDE;
    const int old = __hip_atomic_fetch_add(leaf, 1, __ATOMIC_RELAXED,
                                           __HIP_MEMORY_SCOPE_AGENT);
    if (old == NLEAF * k - 1)
      __hip_atomic_store(bar + (NLEAF + 1 + myleaf) * BSTRIDE, k,
                         __ATOMIC_RELAXED, __HIP_MEMORY_SCOPE_AGENT);
    for (;;) {
      int mn = k;
#pragma unroll
      for (int rr = 0; rr < NLEAF; ++rr) {
        const int f = __hip_atomic_load(bar + (NLEAF + 1 + rr) * BSTRIDE,
                                        __ATOMIC_RELAXED,
                                        __HIP_MEMORY_SCOPE_AGENT);
        mn = min(mn, f);
      }
      if (mn >= k) break;
      __builtin_amdgcn_s_sleep(1);
    }
  }
  __syncthreads();
}

// Per-phase stage: coherent W load + scale into LDS (coords are persistent).
__device__ __forceinline__ void stageW(const float* __restrict__ win,
                                       float* __restrict__ sW, int tid) {
  const int c = tid * 4;
  const float w0 = coh_load(win + c + 0), w1 = coh_load(win + c + 1);
  const float w2 = coh_load(win + c + 2), w3 = coh_load(win + c + 3);
  float4 W;
  W.x = w0 * S_L2E;  W.y = w1 * S_L2E;  W.z = w2 * S_L2E;  W.w = w3 * S_L2E;
  *(float4*)(sW + c) = W;
  __syncthreads();
}

// One-time coord stage: scaled column coords into LDS (4 cols/thread).
__device__ __forceinline__ void stageCoords(const float* __restrict__ colp,
                                            float* __restrict__ sC0,
                                            float* __restrict__ sC1, int tid) {
  const int c = tid * 4;
  const float4 a = ((const float4*)colp)[(c >> 1) + 0];  // (x0,y0,x1,y1)
  const float4 b = ((const float4*)colp)[(c >> 1) + 1];  // (x2,y2,x3,y3)
  float4 C0, C1;
  C0.x = a.x * S_L2E; C0.y = a.z * S_L2E; C0.z = b.x * S_L2E; C0.w = b.z * S_L2E;
  C1.x = a.y * S_L2E; C1.y = a.w * S_L2E; C1.z = b.y * S_L2E; C1.w = b.w * S_L2E;
  *(float4*)(sC0 + c) = C0;
  *(float4*)(sC1 + c) = C1;
}

// u-phase: W from LDS, D from registers. Combine identical to round-3/6.
__device__ __forceinline__ void phaseU(const float* __restrict__ sW,
                                       const float (&Dreg)[NJT][RPW][4],
                                       float (*sPart)[RPW],
                                       float* __restrict__ wout,
                                       int row0blk, int wv, int lane, int tid,
                                       int base) {
  float acc0 = 0.f, acc1 = 0.f;
#pragma unroll
  for (int jt = 0; jt < NJT; ++jt) {
    const int j = base + jt * 256;
    const float4 W = *(const float4*)(sW + j);
    acc0 += (fexp2(W.x - Dreg[jt][0][0]) + fexp2(W.y - Dreg[jt][0][1])) +
            (fexp2(W.z - Dreg[jt][0][2]) + fexp2(W.w - Dreg[jt][0][3]));
    acc1 += (fexp2(W.x - Dreg[jt][1][0]) + fexp2(W.y - Dreg[jt][1][1])) +
            (fexp2(W.z - Dreg[jt][1][2]) + fexp2(W.w - Dreg[jt][1][3]));
  }
  const float S0 = wave_sum64(acc0);
  const float S1 = wave_sum64(acc1);
  if (lane == 0) { sPart[wv][0] = S0; sPart[wv][1] = S1; }
  __syncthreads();
  if (tid < 16) {
    const int p = tid >> 1, r = tid & 1;
    const float S = sPart[2 * p][r] + sPart[2 * p + 1][r];
    coh_store(wout + row0blk + p * RPW + r, A_LOGMU - EPS_F * __logf(S));
  }
}

// v-phase: verbatim round-3/6 phase() against persistent x-coords.
__device__ __forceinline__ void phaseV(const float* __restrict__ rx,
                                       const float* __restrict__ ry,
                                       const float* __restrict__ sW,
                                       const float* __restrict__ sC0,
                                       const float* __restrict__ sC1,
                                       float (*sPart)[RPW],
                                       float* __restrict__ wout,
                                       int row0blk, int wv, int lane, int tid,
                                       int base) {
  float acc0 = 0.f, acc1 = 0.f;
#pragma unroll
  for (int jt = 0; jt < NJT; ++jt) {
    const int j = base + jt * 256;
    const float4 W  = *(const float4*)(sW + j);
    const float4 C0 = *(const float4*)(sC0 + j);
    const float4 C1 = *(const float4*)(sC1 + j);
    {
      const float a0 = (W.x - fabsf(rx[0] - C0.x)) - fabsf(ry[0] - C1.x);
      const float a1 = (W.y - fabsf(rx[0] - C0.y)) - fabsf(ry[0] - C1.y);
      const float a2 = (W.z - fabsf(rx[0] - C0.z)) - fabsf(ry[0] - C1.z);
      const float a3 = (W.w - fabsf(rx[0] - C0.w)) - fabsf(ry[0] - C1.w);
      acc0 += (fexp2(a0) + fexp2(a1)) + (fexp2(a2) + fexp2(a3));
    }
    {
      const float a0 = (W.x - fabsf(rx[1] - C0.x)) - fabsf(ry[1] - C1.x);
      const float a1 = (W.y - fabsf(rx[1] - C0.y)) - fabsf(ry[1] - C1.y);
      const float a2 = (W.z - fabsf(rx[1] - C0.z)) - fabsf(ry[1] - C1.z);
      const float a3 = (W.w - fabsf(rx[1] - C0.w)) - fabsf(ry[1] - C1.w);
      acc1 += (fexp2(a0) + fexp2(a1)) + (fexp2(a2) + fexp2(a3));
    }
  }
  const float S0 = wave_sum64(acc0);
  const float S1 = wave_sum64(acc1);
  if (lane == 0) { sPart[wv][0] = S0; sPart[wv][1] = S1; }
  __syncthreads();
  if (tid < 16) {
    const int p = tid >> 1, r = tid & 1;
    const float S = sPart[2 * p][r] + sPart[2 * p + 1][r];
    coh_store(wout + row0blk + p * RPW + r, A_LOGMU - EPS_F * __logf(S));
  }
}

__global__ void __launch_bounds__(TPB, 4)
sinkhorn_main(const float* __restrict__ x, const float* __restrict__ y,
              float* __restrict__ u, float* __restrict__ v,
              float* __restrict__ out, int* __restrict__ bar) {
  __shared__ float sW[NPTS];
  __shared__ float sC0y[NPTS], sC1y[NPTS];    // y cols (u-phase precompute/epi)
  __shared__ float sC0x[NPTS], sC1x[NPTS];    // x cols (v-phase)
  __shared__ float sPart[WPB][RPW];
  __shared__ float sCost[WPB];

  const int tid  = threadIdx.x;
  const int wv   = tid >> 6;
  const int lane = tid & 63;
  const int row0blk = blockIdx.x * (WPB / 2) * RPW;        // 16 rows per block
  const int row0 = row0blk + (wv >> 1) * RPW;              // this wave's rows
  const int base = (wv & 1) * HALFC + lane * 4;

  float rxu[RPW], ryu[RPW], rxv[RPW], ryv[RPW];
#pragma unroll
  for (int r = 0; r < RPW; ++r) {
    const float2 xr = ((const float2*)x)[row0 + r];
    const float2 yr = ((const float2*)y)[row0 + r];
    rxu[r] = xr.x * S_L2E;  ryu[r] = xr.y * S_L2E;
    rxv[r] = yr.x * S_L2E;  ryv[r] = yr.y * S_L2E;
  }

  stageCoords(y, sC0y, sC1y, tid);
  stageCoords(x, sC0x, sC1x, tid);
  __syncthreads();

  // Iteration-invariant scaled distances for this thread's u-phase footprint.
  float Dreg[NJT][RPW][4];
#pragma unroll
  for (int jt = 0; jt < NJT; ++jt) {
    const int j = base + jt * 256;
    const float4 C0 = *(const float4*)(sC0y + j);
    const float4 C1 = *(const float4*)(sC1y + j);
#pragma unroll
    for (int r = 0; r < RPW; ++r) {
      Dreg[jt][r][0] = fabsf(rxu[r] - C0.x) + fabsf(ryu[r] - C1.x);
      Dreg[jt][r][1] = fabsf(rxu[r] - C0.y) + fabsf(ryu[r] - C1.y);
      Dreg[jt][r][2] = fabsf(rxu[r] - C0.z) + fabsf(ryu[r] - C1.z);
      Dreg[jt][r][3] = fabsf(rxu[r] - C0.w) + fabsf(ryu[r] - C1.w);
    }
  }

  int k = 0;
  for (int it = 0; it < N_ITER; ++it) {
    stageW(v, sW, tid);                                     // win = v
    phaseU(sW, Dreg, sPart, u, row0blk, wv, lane, tid, base);
    grid_barrier(bar, ++k);
    stageW(u, sW, tid);                                     // win = u
    phaseV(rxv, ryv, sW, sC0x, sC1x, sPart, v, row0blk, wv, lane, tid, base);
    grid_barrier(bar, ++k);
  }
  stageW(v, sW, tid);                                       // final v

  // ---- output: out[0]=cost, out[1..]=pi, out[1+N*N..]=C ----
  float* __restrict__ pi = out + 1;
  float* __restrict__ cm = out + 1 + (size_t)NPTS * NPTS;
  float uu[RPW];
#pragma unroll
  for (int r = 0; r < RPW; ++r) uu[r] = coh_load(u + row0 + r) * S_L2E;

  float costacc = 0.f;
#pragma unroll
  for (int jt = 0; jt < NJT; ++jt) {          // full unroll: Dreg idx static
    const int j = base + jt * 256;
    const float4 W = *(const float4*)(sW + j);
#pragma unroll
    for (int r = 0; r < RPW; ++r) {
      const float s0 = Dreg[jt][r][0];
      const float s1 = Dreg[jt][r][1];
      const float s2 = Dreg[jt][r][2];
      const float s3 = Dreg[jt][r][3];
      const float p0 = fexp2((uu[r] + W.x) - s0);
      const float p1 = fexp2((uu[r] + W.y) - s1);
      const float p2 = fexp2((uu[r] + W.z) - s2);
      const float p3 = fexp2((uu[r] + W.w) - s3);
      costacc = fmaf(p0, s0, costacc);
      costacc = fmaf(p1, s1, costacc);
      costacc = fmaf(p2, s2, costacc);
      costacc = fmaf(p3, s3, costacc);
      const size_t off = (size_t)(row0 + r) * NPTS + j;
      f4u pv; pv.x = p0; pv.y = p1; pv.z = p2; pv.w = p3;
      f4u cv; cv.x = s0 * INV_SL; cv.y = s1 * INV_SL;
      cv.z = s2 * INV_SL; cv.w = s3 * INV_SL;
      *(f4u*)(pi + off) = pv;   // out+1 base is 4B-aligned; f4u is aligned(4)
      *(f4u*)(cm + off) = cv;
    }
  }
  const float cw = wave_sum64(costacc);
  if (lane == 0) sCost[wv] = cw;
  __syncthreads();
  if (tid == 0) {
    float c = 0.f;
#pragma unroll
    for (int w = 0; w < WPB; ++w) c += sCost[w];
    atomicAdd(out, c * INV_SL);
  }
}

__global__ void sinkhorn_init(float* __restrict__ v, int* __restrict__ bar,
                              float* __restrict__ out) {
  const int i = blockIdx.x * blockDim.x + threadIdx.x;
  if (i < NPTS) coh_store(v + i, 0.f);
  if (i < BAR_INTS)
    __hip_atomic_store(bar + i, 0, __ATOMIC_RELAXED, __HIP_MEMORY_SCOPE_AGENT);
  if (i == 0) out[0] = 0.f;
}

extern "C" void kernel_launch(void* const* d_in, const int* in_sizes, int n_in,
                              void* d_out, int out_size, void* d_ws, size_t ws_size,
                              hipStream_t stream) {
  const float* x = (const float*)d_in[0];
  const float* y = (const float*)d_in[1];
  float* u = (float*)d_ws;
  float* v = u + NPTS;
  int* bar = (int*)(v + NPTS);
  float* out = (float*)d_out;

  sinkhorn_init<<<dim3(16), dim3(256), 0, stream>>>(v, bar, out);

  void* args[6];
  args[0] = (void*)&x;
  args[1] = (void*)&y;
  args[2] = (void*)&u;
  args[3] = (void*)&v;
  args[4] = (void*)&out;
  args[5] = (void*)&bar;
  hipLaunchCooperativeKernel((void*)sinkhorn_main, dim3(NBLK), dim3(TPB),
                             args, 0, stream);
}

// Round 6
// 685.435 us; speedup vs baseline: 1.4729x; 1.0044x over previous
//
#include <hip/hip_runtime.h>

// Sinkhorn, N=4096, D=2, P=1, eps=0.1, 50 iters — persistent cooperative kernel.
// Round-9: round-8 (577 us profiled, VERIFIED) + Dreg actually in registers.
// Round-8's VGPR_Count=64 proved the compiler REMATERIALIZED the 64-float
// u-phase distance cache from LDS coords every iteration (64 regs can't hold
// it; no scratch traffic). Fix: identity `asm volatile("" : "+v")` pin on each
// Dreg value after the one-time precompute — values become opaque, compiler
// must keep them live in VGPRs (~110 total < 128 cap, occupancy unchanged).
// phaseU: ~8 -> ~3 inst/element. Everything else verbatim round-8.

#define NPTS    4096
#define EPS_F   0.1f
#define S_L2E   14.426950408889634f     /* log2(e)/eps */
#define INV_SL  0.0693147180559945f     /* 1/S_L2E = eps*ln2 */
#define A_LOGMU (-0.8317725207f)        /* eps * ln(1/N + 1e-8) */
#define N_ITER  50
#define NBLK    256
#define TPB     1024
#define WPB     (TPB / 64)              /* 16 waves/block */
#define RPW     2                       /* rows per wave (wave-pair shares rows) */
#define HALFC   2048                    /* columns per wave (pair splits 4096) */
#define NJT     (HALFC / 256)           /* 8 j-tiles of 64 lanes x 4 cols */
#define NLEAF   16
#define BSTRIDE 64                      /* ints between barrier words = 256 B */
/* layout: leaf i at i*BSTRIDE (i<16); [16] unused; leafdone r at (17+r)*BSTRIDE */
#define BAR_INTS ((NLEAF + 1 + NLEAF) * BSTRIDE)

typedef float f4u __attribute__((ext_vector_type(4), aligned(4)));

__device__ __forceinline__ float fexp2(float x) {
#if __has_builtin(__builtin_amdgcn_exp2f)
  return __builtin_amdgcn_exp2f(x);
#else
  float r;
  asm("v_exp_f32 %0, %1" : "=v"(r) : "v"(x));
  return r;
#endif
}

__device__ __forceinline__ float coh_load(const float* p) {
  return __hip_atomic_load(p, __ATOMIC_RELAXED, __HIP_MEMORY_SCOPE_AGENT);
}
__device__ __forceinline__ void coh_store(float* p, float x) {
  __hip_atomic_store(p, x, __ATOMIC_RELAXED, __HIP_MEMORY_SCOPE_AGENT);
}

__device__ __forceinline__ float wave_sum64(float x) {
#pragma unroll
  for (int off = 32; off > 0; off >>= 1) x += __shfl_xor(x, off, 64);
  return x;
}

// Flattened tree barrier, all ops RELAXED AGENT — verbatim round-8 (verified).
__device__ __forceinline__ void grid_barrier(int* bar, int k) {
  __syncthreads();
  if (threadIdx.x == 0) {
    const int myleaf = blockIdx.x & (NLEAF - 1);
    int* leaf = bar + myleaf * BSTRIDE;
    const int old = __hip_atomic_fetch_add(leaf, 1, __ATOMIC_RELAXED,
                                           __HIP_MEMORY_SCOPE_AGENT);
    if (old == NLEAF * k - 1)
      __hip_atomic_store(bar + (NLEAF + 1 + myleaf) * BSTRIDE, k,
                         __ATOMIC_RELAXED, __HIP_MEMORY_SCOPE_AGENT);
    for (;;) {
      int mn = k;
#pragma unroll
      for (int rr = 0; rr < NLEAF; ++rr) {
        const int f = __hip_atomic_load(bar + (NLEAF + 1 + rr) * BSTRIDE,
                                        __ATOMIC_RELAXED,
                                        __HIP_MEMORY_SCOPE_AGENT);
        mn = min(mn, f);
      }
      if (mn >= k) break;
      __builtin_amdgcn_s_sleep(1);
    }
  }
  __syncthreads();
}

// Per-phase stage: coherent W load + scale into LDS (coords are persistent).
__device__ __forceinline__ void stageW(const float* __restrict__ win,
                                       float* __restrict__ sW, int tid) {
  const int c = tid * 4;
  const float w0 = coh_load(win + c + 0), w1 = coh_load(win + c + 1);
  const float w2 = coh_load(win + c + 2), w3 = coh_load(win + c + 3);
  float4 W;
  W.x = w0 * S_L2E;  W.y = w1 * S_L2E;  W.z = w2 * S_L2E;  W.w = w3 * S_L2E;
  *(float4*)(sW + c) = W;
  __syncthreads();
}

// One-time coord stage: scaled column coords into LDS (4 cols/thread).
__device__ __forceinline__ void stageCoords(const float* __restrict__ colp,
                                            float* __restrict__ sC0,
                                            float* __restrict__ sC1, int tid) {
  const int c = tid * 4;
  const float4 a = ((const float4*)colp)[(c >> 1) + 0];  // (x0,y0,x1,y1)
  const float4 b = ((const float4*)colp)[(c >> 1) + 1];  // (x2,y2,x3,y3)
  float4 C0, C1;
  C0.x = a.x * S_L2E; C0.y = a.z * S_L2E; C0.z = b.x * S_L2E; C0.w = b.z * S_L2E;
  C1.x = a.y * S_L2E; C1.y = a.w * S_L2E; C1.z = b.y * S_L2E; C1.w = b.w * S_L2E;
  *(float4*)(sC0 + c) = C0;
  *(float4*)(sC1 + c) = C1;
}

// u-phase: W from LDS, D from pinned registers. Combine identical to round-3/6.
__device__ __forceinline__ void phaseU(const float* __restrict__ sW,
                                       const float (&Dreg)[NJT][RPW][4],
                                       float (*sPart)[RPW],
                                       float* __restrict__ wout,
                                       int row0blk, int wv, int lane, int tid,
                                       int base) {
  float acc0 = 0.f, acc1 = 0.f;
#pragma unroll
  for (int jt = 0; jt < NJT; ++jt) {
    const int j = base + jt * 256;
    const float4 W = *(const float4*)(sW + j);
    acc0 += (fexp2(W.x - Dreg[jt][0][0]) + fexp2(W.y - Dreg[jt][0][1])) +
            (fexp2(W.z - Dreg[jt][0][2]) + fexp2(W.w - Dreg[jt][0][3]));
    acc1 += (fexp2(W.x - Dreg[jt][1][0]) + fexp2(W.y - Dreg[jt][1][1])) +
            (fexp2(W.z - Dreg[jt][1][2]) + fexp2(W.w - Dreg[jt][1][3]));
  }
  const float S0 = wave_sum64(acc0);
  const float S1 = wave_sum64(acc1);
  if (lane == 0) { sPart[wv][0] = S0; sPart[wv][1] = S1; }
  __syncthreads();
  if (tid < 16) {
    const int p = tid >> 1, r = tid & 1;
    const float S = sPart[2 * p][r] + sPart[2 * p + 1][r];
    coh_store(wout + row0blk + p * RPW + r, A_LOGMU - EPS_F * __logf(S));
  }
}

// v-phase: verbatim round-3/6 phase() against persistent x-coords.
__device__ __forceinline__ void phaseV(const float* __restrict__ rx,
                                       const float* __restrict__ ry,
                                       const float* __restrict__ sW,
                                       const float* __restrict__ sC0,
                                       const float* __restrict__ sC1,
                                       float (*sPart)[RPW],
                                       float* __restrict__ wout,
                                       int row0blk, int wv, int lane, int tid,
                                       int base) {
  float acc0 = 0.f, acc1 = 0.f;
#pragma unroll
  for (int jt = 0; jt < NJT; ++jt) {
    const int j = base + jt * 256;
    const float4 W  = *(const float4*)(sW + j);
    const float4 C0 = *(const float4*)(sC0 + j);
    const float4 C1 = *(const float4*)(sC1 + j);
    {
      const float a0 = (W.x - fabsf(rx[0] - C0.x)) - fabsf(ry[0] - C1.x);
      const float a1 = (W.y - fabsf(rx[0] - C0.y)) - fabsf(ry[0] - C1.y);
      const float a2 = (W.z - fabsf(rx[0] - C0.z)) - fabsf(ry[0] - C1.z);
      const float a3 = (W.w - fabsf(rx[0] - C0.w)) - fabsf(ry[0] - C1.w);
      acc0 += (fexp2(a0) + fexp2(a1)) + (fexp2(a2) + fexp2(a3));
    }
    {
      const float a0 = (W.x - fabsf(rx[1] - C0.x)) - fabsf(ry[1] - C1.x);
      const float a1 = (W.y - fabsf(rx[1] - C0.y)) - fabsf(ry[1] - C1.y);
      const float a2 = (W.z - fabsf(rx[1] - C0.z)) - fabsf(ry[1] - C1.z);
      const float a3 = (W.w - fabsf(rx[1] - C0.w)) - fabsf(ry[1] - C1.w);
      acc1 += (fexp2(a0) + fexp2(a1)) + (fexp2(a2) + fexp2(a3));
    }
  }
  const float S0 = wave_sum64(acc0);
  const float S1 = wave_sum64(acc1);
  if (lane == 0) { sPart[wv][0] = S0; sPart[wv][1] = S1; }
  __syncthreads();
  if (tid < 16) {
    const int p = tid >> 1, r = tid & 1;
    const float S = sPart[2 * p][r] + sPart[2 * p + 1][r];
    coh_store(wout + row0blk + p * RPW + r, A_LOGMU - EPS_F * __logf(S));
  }
}

__global__ void __launch_bounds__(TPB, 4)
sinkhorn_main(const float* __restrict__ x, const float* __restrict__ y,
              float* __restrict__ u, float* __restrict__ v,
              float* __restrict__ out, int* __restrict__ bar) {
  __shared__ float sW[NPTS];
  __shared__ float sC0y[NPTS], sC1y[NPTS];    // y cols (u-phase precompute/epi)
  __shared__ float sC0x[NPTS], sC1x[NPTS];    // x cols (v-phase)
  __shared__ float sPart[WPB][RPW];
  __shared__ float sCost[WPB];

  const int tid  = threadIdx.x;
  const int wv   = tid >> 6;
  const int lane = tid & 63;
  const int row0blk = blockIdx.x * (WPB / 2) * RPW;        // 16 rows per block
  const int row0 = row0blk + (wv >> 1) * RPW;              // this wave's rows
  const int base = (wv & 1) * HALFC + lane * 4;

  float rxu[RPW], ryu[RPW], rxv[RPW], ryv[RPW];
#pragma unroll
  for (int r = 0; r < RPW; ++r) {
    const float2 xr = ((const float2*)x)[row0 + r];
    const float2 yr = ((const float2*)y)[row0 + r];
    rxu[r] = xr.x * S_L2E;  ryu[r] = xr.y * S_L2E;
    rxv[r] = yr.x * S_L2E;  ryv[r] = yr.y * S_L2E;
  }

  stageCoords(y, sC0y, sC1y, tid);
  stageCoords(x, sC0x, sC1x, tid);
  __syncthreads();

  // Iteration-invariant scaled distances for this thread's u-phase footprint.
  float Dreg[NJT][RPW][4];
#pragma unroll
  for (int jt = 0; jt < NJT; ++jt) {
    const int j = base + jt * 256;
    const float4 C0 = *(const float4*)(sC0y + j);
    const float4 C1 = *(const float4*)(sC1y + j);
#pragma unroll
    for (int r = 0; r < RPW; ++r) {
      Dreg[jt][r][0] = fabsf(rxu[r] - C0.x) + fabsf(ryu[r] - C1.x);
      Dreg[jt][r][1] = fabsf(rxu[r] - C0.y) + fabsf(ryu[r] - C1.y);
      Dreg[jt][r][2] = fabsf(rxu[r] - C0.z) + fabsf(ryu[r] - C1.z);
      Dreg[jt][r][3] = fabsf(rxu[r] - C0.w) + fabsf(ryu[r] - C1.w);
    }
  }
  // Pin Dreg: identity asm makes each value opaque so the compiler CANNOT
  // rematerialize it from LDS coords inside the iteration loop (round-8's
  // VGPR_Count=64 proved it was doing exactly that). ~110 VGPR < 128 cap.
#pragma unroll
  for (int jt = 0; jt < NJT; ++jt)
#pragma unroll
    for (int r = 0; r < RPW; ++r)
      asm volatile("" : "+v"(Dreg[jt][r][0]), "+v"(Dreg[jt][r][1]),
                        "+v"(Dreg[jt][r][2]), "+v"(Dreg[jt][r][3]));

  int k = 0;
  for (int it = 0; it < N_ITER; ++it) {
    stageW(v, sW, tid);                                     // win = v
    phaseU(sW, Dreg, sPart, u, row0blk, wv, lane, tid, base);
    grid_barrier(bar, ++k);
    stageW(u, sW, tid);                                     // win = u
    phaseV(rxv, ryv, sW, sC0x, sC1x, sPart, v, row0blk, wv, lane, tid, base);
    grid_barrier(bar, ++k);
  }
  stageW(v, sW, tid);                                       // final v

  // ---- output: out[0]=cost, out[1..]=pi, out[1+N*N..]=C ----
  float* __restrict__ pi = out + 1;
  float* __restrict__ cm = out + 1 + (size_t)NPTS * NPTS;
  float uu[RPW];
#pragma unroll
  for (int r = 0; r < RPW; ++r) uu[r] = coh_load(u + row0 + r) * S_L2E;

  float costacc = 0.f;
#pragma unroll
  for (int jt = 0; jt < NJT; ++jt) {          // full unroll: Dreg idx static
    const int j = base + jt * 256;
    const float4 W = *(const float4*)(sW + j);
#pragma unroll
    for (int r = 0; r < RPW; ++r) {
      const float s0 = Dreg[jt][r][0];
      const float s1 = Dreg[jt][r][1];
      const float s2 = Dreg[jt][r][2];
      const float s3 = Dreg[jt][r][3];
      const float p0 = fexp2((uu[r] + W.x) - s0);
      const float p1 = fexp2((uu[r] + W.y) - s1);
      const float p2 = fexp2((uu[r] + W.z) - s2);
      const float p3 = fexp2((uu[r] + W.w) - s3);
      costacc = fmaf(p0, s0, costacc);
      costacc = fmaf(p1, s1, costacc);
      costacc = fmaf(p2, s2, costacc);
      costacc = fmaf(p3, s3, costacc);
      const size_t off = (size_t)(row0 + r) * NPTS + j;
      f4u pv; pv.x = p0; pv.y = p1; pv.z = p2; pv.w = p3;
      f4u cv; cv.x = s0 * INV_SL; cv.y = s1 * INV_SL;
      cv.z = s2 * INV_SL; cv.w = s3 * INV_SL;
      *(f4u*)(pi + off) = pv;   // out+1 base is 4B-aligned; f4u is aligned(4)
      *(f4u*)(cm + off) = cv;
    }
  }
  const float cw = wave_sum64(costacc);
  if (lane == 0) sCost[wv] = cw;
  __syncthreads();
  if (tid == 0) {
    float c = 0.f;
#pragma unroll
    for (int w = 0; w < WPB; ++w) c += sCost[w];
    atomicAdd(out, c * INV_SL);
  }
}

__global__ void sinkhorn_init(float* __restrict__ v, int* __restrict__ bar,
                              float* __restrict__ out) {
  const int i = blockIdx.x * blockDim.x + threadIdx.x;
  if (i < NPTS) coh_store(v + i, 0.f);
  if (i < BAR_INTS)
    __hip_atomic_store(bar + i, 0, __ATOMIC_RELAXED, __HIP_MEMORY_SCOPE_AGENT);
  if (i == 0) out[0] = 0.f;
}

extern "C" void kernel_launch(void* const* d_in, const int* in_sizes, int n_in,
                              void* d_out, int out_size, void* d_ws, size_t ws_size,
                              hipStream_t stream) {
  const float* x = (const float*)d_in[0];
  const float* y = (const float*)d_in[1];
  float* u = (float*)d_ws;
  float* v = u + NPTS;
  int* bar = (int*)(v + NPTS);
  float* out = (float*)d_out;

  sinkhorn_init<<<dim3(16), dim3(256), 0, stream>>>(v, bar, out);

  void* args[6];
  args[0] = (void*)&x;
  args[1] = (void*)&y;
  args[2] = (void*)&u;
  args[3] = (void*)&v;
  args[4] = (void*)&out;
  args[5] = (void*)&bar;
  hipLaunchCooperativeKernel((void*)sinkhorn_main, dim3(NBLK), dim3(TPB),
                             args, 0, stream);
}